// Round 1
// baseline (64.435 us; speedup 1.0000x reference)
//
#include <hip/hip_runtime.h>
#include <math.h>

// Problem constants (from reference)
#define T_LEN 200
#define B_SZ  4096
#define V_SZ  100000
#define PAD_TOK 1
#define HASH_SIZE 1024   // power of 2, load factor 200/1024

__global__ __launch_bounds__(256) void bow_sigmoid_kernel(
    const int*   __restrict__ text,   // [T, B] int32 token ids
    const float* __restrict__ W,      // [1, V] weights
    const float* __restrict__ bias,   // [1]
    float*       __restrict__ out)    // [B, 1]
{
    __shared__ int   hset[HASH_SIZE];
    __shared__ float wave_sums[4];

    const int tid = threadIdx.x;

    // XCD-aware swizzle: MI355X dispatches blocks round-robin across 8 XCDs.
    // Map so consecutive batch columns (sharing text cache lines) stay on one XCD.
    const int blk = blockIdx.x;
    const int b = (blk & 7) * (B_SZ / 8) + (blk >> 3);

    // Clear hash set (sentinel -1; token 0 is a valid id)
    for (int i = tid; i < HASH_SIZE; i += 256) hset[i] = -1;
    __syncthreads();

    float sum = 0.0f;
    if (tid < T_LEN) {
        const int tok = text[tid * B_SZ + b];
        if (tok != PAD_TOK) {
            unsigned h = ((unsigned)tok * 2654435761u) & (HASH_SIZE - 1);
            for (;;) {
                const int old = atomicCAS(&hset[h], -1, tok);
                if (old == -1) {           // first insertion of this token: count it
                    sum = W[tok];
                    break;
                }
                if (old == tok) break;     // duplicate within sequence: set semantics, skip
                h = (h + 1) & (HASH_SIZE - 1);
            }
        }
    }
    __syncthreads();  // all inserts complete (also orders LDS reuse below)

    // Wave-64 reduction
    #pragma unroll
    for (int off = 32; off > 0; off >>= 1)
        sum += __shfl_down(sum, off, 64);
    if ((tid & 63) == 0) wave_sums[tid >> 6] = sum;
    __syncthreads();

    if (tid == 0) {
        const float s = wave_sums[0] + wave_sums[1] + wave_sums[2] + wave_sums[3] + bias[0];
        out[b] = 1.0f / (1.0f + expf(-s));
    }
}

extern "C" void kernel_launch(void* const* d_in, const int* in_sizes, int n_in,
                              void* d_out, int out_size, void* d_ws, size_t ws_size,
                              hipStream_t stream) {
    const int*   text = (const int*)d_in[0];    // [200, 4096] int32
    const float* W    = (const float*)d_in[1];  // [1, 100000]
    const float* bias = (const float*)d_in[2];  // [1]
    float*       out  = (float*)d_out;          // [4096, 1]

    bow_sigmoid_kernel<<<B_SZ, 256, 0, stream>>>(text, W, bias, out);
}